// Round 10
// baseline (223.040 us; speedup 1.0000x reference)
//
#include <hip/hip_runtime.h>

#define N 9216
#define CIN 256
#define DQ 32
#define NT 144                      // N / 64 (Opart n-chunk count)
#define NT2 72                      // N / 128 (attn n-tile count)
#define LOG2E 1.44269504088896340736f

typedef short short8 __attribute__((ext_vector_type(8)));   // 8 bf16 in 4 VGPRs
typedef float floatx4 __attribute__((ext_vector_type(4)));
typedef unsigned short ushort_t;

__device__ __forceinline__ ushort_t f2bf(float f) {
  union { float f; unsigned u; } a; a.f = f;
  unsigned u = a.u;
  u += 0x7fffu + ((u >> 16) & 1u);   // round-to-nearest-even
  return (ushort_t)(u >> 16);
}
// cheap round-to-nearest: 2 VALU ops instead of 5.
__device__ __forceinline__ ushort_t f2bf_fast(float f) {
  union { float f; unsigned u; } a; a.f = f;
  return (ushort_t)((a.u + 0x8000u) >> 16);
}
__device__ __forceinline__ float bf2f(ushort_t h) {
  union { unsigned u; float f; } a; a.u = ((unsigned)h) << 16;
  return a.f;
}
// pack two floats -> one uint of 2 bf16 (lo = c, hi = c1)
__device__ __forceinline__ unsigned pack2(float lo, float hi) {
  return ((unsigned)f2bf_fast(hi) << 16) | (unsigned)f2bf_fast(lo);
}
// 8 consecutive fp32 -> bf16x8 A-fragment
__device__ __forceinline__ short8 mk_bf16x8(const float* p) {
  float4 f0 = *(const float4*)(p);
  float4 f1 = *(const float4*)(p + 4);
  union { unsigned u[4]; short8 v; } r;
  r.u[0] = pack2(f0.x, f0.y);
  r.u[1] = pack2(f0.z, f0.w);
  r.u[2] = pack2(f1.x, f1.y);
  r.u[3] = pack2(f1.z, f1.w);
  return r.v;
}

// ---------------------------------------------------------------------------
// Shared staging: x tile (256 c x 64 n) -> LDS bf16 xbT[n][k=c].
// ---------------------------------------------------------------------------
#define XBT_STRIDE 264   // ushorts per row (256 + 8 pad); 132 uints

__device__ __forceinline__ void stage_x_tile(
    const float* __restrict__ x, int n0, int t, ushort_t (*xbT)[XBT_STRIDE])
{
  const int p = t & 31, ng = t >> 5;          // ng in [0,8)
  unsigned* base = (unsigned*)&xbT[0][0] + (size_t)(ng * 8) * 132;
#pragma unroll
  for (int cc = 0; cc < 4; ++cc) {
    const int c = cc * 64 + 2 * p;
    const float* r0 = x + (size_t)c * N + n0 + ng * 8;
    const float* r1 = r0 + N;
    float4 a0 = *(const float4*)(r0);
    float4 a1 = *(const float4*)(r0 + 4);
    float4 b0 = *(const float4*)(r1);
    float4 b1 = *(const float4*)(r1 + 4);
    unsigned* d = base + (cc * 32 + p);
    d[0 * 132] = pack2(a0.x, b0.x);
    d[1 * 132] = pack2(a0.y, b0.y);
    d[2 * 132] = pack2(a0.z, b0.z);
    d[3 * 132] = pack2(a0.w, b0.w);
    d[4 * 132] = pack2(a1.x, b1.x);
    d[5 * 132] = pack2(a1.y, b1.y);
    d[6 * 132] = pack2(a1.z, b1.z);
    d[7 * 132] = pack2(a1.w, b1.w);
  }
}

// ---------------------------------------------------------------------------
// Kernel 1: q/k/v projections via bf16 MFMA.  UNCHANGED (control).
// ---------------------------------------------------------------------------
__global__ __launch_bounds__(256) void qkv_mfma(
    const float* __restrict__ x,
    const float* __restrict__ Wq, const float* __restrict__ bq,
    const float* __restrict__ Wk, const float* __restrict__ bk,
    const float* __restrict__ Wv, const float* __restrict__ bv,
    ushort_t* __restrict__ qT, ushort_t* __restrict__ kT,
    ushort_t* __restrict__ vG, float* __restrict__ sumExp)
{
  if (blockIdx.x == 0 && blockIdx.y == 0 && threadIdx.x == 0) *sumExp = 0.f;

  __shared__ ushort_t xbT[64][XBT_STRIDE];
  const int t = threadIdx.x;
  const int n0 = blockIdx.x * 64;
  const int oc = blockIdx.y;                 // 0: q(32)+k(32); 1..4: v
  const int w = t >> 6, lane = t & 63;
  const int quad = lane >> 4, l15 = lane & 15;

  stage_x_tile(x, n0, t, xbT);
  __syncthreads();

  const int obase = oc * 64 + w * 16;
  const int oA = obase + l15;                // A-frag row (m = l15)
  const float* Arow;
  if (oc == 0) Arow = (obase < 32) ? (Wq + (size_t)oA * CIN)
                                   : (Wk + (size_t)(oA - 32) * CIN);
  else         Arow = Wv + (size_t)(oA - 64) * CIN;

  floatx4 acc[4];
#pragma unroll
  for (int b2 = 0; b2 < 4; ++b2) acc[b2] = (floatx4){0.f, 0.f, 0.f, 0.f};

#pragma unroll
  for (int ks = 0; ks < 8; ++ks) {
    const short8 af = mk_bf16x8(Arow + ks * 32 + 8 * quad);
#pragma unroll
    for (int b2 = 0; b2 < 4; ++b2) {
      const short8 bf = *(const short8*)&xbT[b2 * 16 + l15][ks * 32 + 8 * quad];
      acc[b2] = __builtin_amdgcn_mfma_f32_16x16x32_bf16(af, bf, acc[b2], 0, 0, 0);
    }
  }

#pragma unroll
  for (int b2 = 0; b2 < 4; ++b2) {
    const int n = n0 + b2 * 16 + l15;
#pragma unroll
    for (int r = 0; r < 4; ++r) {
      const int o = obase + 4 * quad + r;
      const float val = acc[b2][r];
      if (oc == 0) {
        if (o < 32) qT[(size_t)n * DQ + o]        = f2bf((val + bq[o]) * LOG2E);
        else        kT[(size_t)n * DQ + (o - 32)] = f2bf(val + bk[o - 32]);
      } else        vG[(size_t)(o - 64) * N + n]  = f2bf(val + bv[o - 64]);
    }
  }
}

// ---------------------------------------------------------------------------
// Kernel 2: flash attention, 128-n blocks x 512 threads (8 waves).
// R9 theory: attn plateau is shared V-read bandwidth (680 MB through L2/L3
// in 115 us).  Waves w and w+4 share identical V fragments (same c-range
// (w&3)*64, same m) for different n-halves (w>>2) -> L1 dedup halves V
// traffic to 340 MB.  Per-wave register profile unchanged (64 VGPR + 64 AGPR
// = 4 waves/SIMD); grid 72 x nsl=7 = 504 blocks = one round at 2 blocks/CU.
// ---------------------------------------------------------------------------
__global__ __launch_bounds__(512, 4) void attn_kernel(
    const ushort_t* __restrict__ qT, const ushort_t* __restrict__ kT,
    const ushort_t* __restrict__ vG,
    ushort_t* __restrict__ Opart, float* __restrict__ lpart,
    int base, int rem)
{
  __shared__ ushort_t Pb[2][128][36];   // double-buffered P tile (128n x 32m)

  const int t = threadIdx.x;
  const int w = t >> 6;                 // 0..7
  const int lane = t & 63;
  const int quad = lane >> 4;
  const int l15 = lane & 15;
  const int nt = blockIdx.x;            // 0..71
  const int s  = blockIdx.y;
  const int n0 = nt * 128;
  const int sliceIters = base + (s < rem ? 1 : 0);
  const int it0 = s * base + (s < rem ? s : rem);
  const int mbase = it0 * 32;
  const int cw = (w & 3) * 64;          // c-range of this wave's O strip
  const int nh = w >> 2;                // n-half of this wave's O strip

  // S producer: wave w owns S rows [n0+16w, n0+16w+16).
  short8 aq = *(const short8*)(qT + (size_t)(n0 + 16 * w + l15) * DQ + 8 * quad);

  floatx4 acc[4][4];
#pragma unroll
  for (int a2 = 0; a2 < 4; ++a2)
#pragma unroll
    for (int b2 = 0; b2 < 4; ++b2)
      acc[a2][b2] = (floatx4){0.f, 0.f, 0.f, 0.f};
  float lsum[4] = {0.f, 0.f, 0.f, 0.f};
  const floatx4 z4 = {0.f, 0.f, 0.f, 0.f};

  for (int it = 0; it < sliceIters; ++it) {
    const int m0 = mbase + it * 32;

    short8 kb0 = *(const short8*)(kT + (size_t)(m0 + l15) * DQ + 8 * quad);
    short8 kb1 = *(const short8*)(kT + (size_t)(m0 + 16 + l15) * DQ + 8 * quad);
    floatx4 s0 = __builtin_amdgcn_mfma_f32_16x16x32_bf16(aq, kb0, z4, 0, 0, 0);
    floatx4 s1 = __builtin_amdgcn_mfma_f32_16x16x32_bf16(aq, kb1, z4, 0, 0, 0);

    // V A-frags: identical addresses for waves w and w+4 -> L1 dedup.
    const ushort_t* vb = vG + (size_t)m0 + 8 * quad;
    short8 av0 = *(const short8*)(vb + (size_t)(cw +  0 + l15) * N);
    short8 av1 = *(const short8*)(vb + (size_t)(cw + 16 + l15) * N);
    short8 av2 = *(const short8*)(vb + (size_t)(cw + 32 + l15) * N);
    short8 av3 = *(const short8*)(vb + (size_t)(cw + 48 + l15) * N);

    ushort_t* pb = &Pb[it & 1][0][0];
#pragma unroll
    for (int r = 0; r < 4; ++r) {
      float p0 = exp2f(s0[r]);
      float p1 = exp2f(s1[r]);
      lsum[r] += p0 + p1;
      const int row = 16 * w + 4 * quad + r;
      pb[row * 36 + l15]      = f2bf_fast(p0);
      pb[row * 36 + 16 + l15] = f2bf_fast(p1);
    }
    __syncthreads();   // single barrier/iter: double buffer covers WAR hazard

    // O^T += V * P^T for this wave's (c-range, n-half).
#pragma unroll
    for (int b2 = 0; b2 < 4; ++b2) {
      const ushort_t* pr = pb + (nh * 64 + b2 * 16 + l15) * 36 + 8 * quad;
      union { uint2 u2[2]; short8 v; } u;
      u.u2[0] = *(const uint2*)(pr);
      u.u2[1] = *(const uint2*)(pr + 4);
      const short8 pf = u.v;
      acc[0][b2] = __builtin_amdgcn_mfma_f32_16x16x32_bf16(av0, pf, acc[0][b2], 0, 0, 0);
      acc[1][b2] = __builtin_amdgcn_mfma_f32_16x16x32_bf16(av1, pf, acc[1][b2], 0, 0, 0);
      acc[2][b2] = __builtin_amdgcn_mfma_f32_16x16x32_bf16(av2, pf, acc[2][b2], 0, 0, 0);
      acc[3][b2] = __builtin_amdgcn_mfma_f32_16x16x32_bf16(av3, pf, acc[3][b2], 0, 0, 0);
    }
  }

  // sumexp for this wave's 16 S rows
#pragma unroll
  for (int r = 0; r < 4; ++r) {
    float v = lsum[r];
    v += __shfl_xor(v, 1);
    v += __shfl_xor(v, 2);
    v += __shfl_xor(v, 4);
    v += __shfl_xor(v, 8);
    lsum[r] = v;
  }
  if (l15 == 0) {
#pragma unroll
    for (int r = 0; r < 4; ++r)
      lpart[(size_t)s * N + n0 + 16 * w + 4 * quad + r] = lsum[r];
  }

  // store O^T partial, layout [s][n-chunk64][c:256][n:64] (cco-compatible)
  const int ntile64 = 2 * nt + nh;
  const size_t basep = ((size_t)s * NT + ntile64) * 256;
#pragma unroll
  for (int a2 = 0; a2 < 4; ++a2)
#pragma unroll
    for (int b2 = 0; b2 < 4; ++b2)
#pragma unroll
      for (int r = 0; r < 4; ++r) {
        const int c  = cw + a2 * 16 + 4 * quad + r;
        const int nl = b2 * 16 + l15;
        Opart[(basep + c) * 64 + nl] = f2bf(acc[a2][b2][r]);
      }
}

// ---------------------------------------------------------------------------
// Kernel 3: fused combine + gate-exp.  UNCHANGED (control).
// ---------------------------------------------------------------------------
template<int NSL>
__global__ __launch_bounds__(1024) void cco_kernel(
    const ushort_t* __restrict__ Opart, const float* __restrict__ lpart,
    float* __restrict__ e_buf, float* __restrict__ sumExp)
{
  const int nt = blockIdx.x;
  const int t = threadIdx.x;
  const int n = t & 63, ci = t >> 6;   // ci in [0,16)
  float mx = -3.4e38f, sm = 0.f;
#pragma unroll
  for (int k = 0; k < 16; ++k) {
    const int c = ci * 16 + k;
    float val = 0.f;
#pragma unroll
    for (int s2 = 0; s2 < NSL; ++s2)
      val += bf2f(Opart[(((size_t)s2 * NT + nt) * 256 + c) * 64 + n]);
    mx = fmaxf(mx, val);
    sm += val;
  }
  __shared__ float rmx[16][64], rsm[16][64];
  rmx[ci][n] = mx; rsm[ci][n] = sm;
  __syncthreads();
  if (t < 64) {
    float m = rmx[0][t], s = rsm[0][t];
#pragma unroll
    for (int g = 1; g < 16; ++g) { m = fmaxf(m, rmx[g][t]); s += rsm[g][t]; }
    float l = 0.f;
#pragma unroll
    for (int s3 = 0; s3 < NSL; ++s3) l += lpart[(size_t)s3 * N + nt * 64 + t];
    const float oc = (m + s * (1.0f / 256.0f)) / l;
    const float ev = exp2f(oc * (0.0625f * LOG2E));
    e_buf[nt * 64 + t] = ev;
    float vs = ev;
    vs += __shfl_xor(vs, 1);  vs += __shfl_xor(vs, 2);
    vs += __shfl_xor(vs, 4);  vs += __shfl_xor(vs, 8);
    vs += __shfl_xor(vs, 16); vs += __shfl_xor(vs, 32);
    if (t == 0) atomicAdd(sumExp, vs);
  }
}

// ---------------------------------------------------------------------------
// Kernel 4: final 1x1 conv via bf16 MFMA + fp32 epilogue.  UNCHANGED.
// ---------------------------------------------------------------------------
__global__ __launch_bounds__(256) void final_mfma(
    const float* __restrict__ x, const float* __restrict__ W6,
    const float* __restrict__ b6, const float* __restrict__ gamma,
    const float* __restrict__ e_buf, const float* __restrict__ sumExp,
    float* __restrict__ out)
{
  __shared__ ushort_t xbT[64][XBT_STRIDE];
  const int t = threadIdx.x;
  const int n0 = blockIdx.x * 64;
  const int w = t >> 6, lane = t & 63;
  const int quad = lane >> 4, l15 = lane & 15;

  stage_x_tile(x, n0, t, xbT);
  __syncthreads();

  const int obase = blockIdx.y * 64 + w * 16;
  const float* Arow = W6 + (size_t)(obase + l15) * CIN;

  floatx4 acc[4];
#pragma unroll
  for (int b2 = 0; b2 < 4; ++b2) acc[b2] = (floatx4){0.f, 0.f, 0.f, 0.f};

#pragma unroll
  for (int ks = 0; ks < 8; ++ks) {
    const short8 af = mk_bf16x8(Arow + ks * 32 + 8 * quad);
#pragma unroll
    for (int b2 = 0; b2 < 4; ++b2) {
      const short8 bf = *(const short8*)&xbT[b2 * 16 + l15][ks * 32 + 8 * quad];
      acc[b2] = __builtin_amdgcn_mfma_f32_16x16x32_bf16(af, bf, acc[b2], 0, 0, 0);
    }
  }

  const float g1 = 1.0f + gamma[0];
  const float inv = 1.0f / sumExp[0];
#pragma unroll
  for (int b2 = 0; b2 < 4; ++b2) {
    const int n = n0 + b2 * 16 + l15;
    const float xc = e_buf[n] * inv;
#pragma unroll
    for (int r = 0; r < 4; ++r) {
      const int o = obase + 4 * quad + r;
      const float xv = x[(size_t)o * N + n];
      out[(size_t)o * N + n] = xv + g1 * (xc * acc[b2][r] + b6[o]);
    }
  }
}

// ---------------------------------------------------------------------------
extern "C" void kernel_launch(void* const* d_in, const int* in_sizes, int n_in,
                              void* d_out, int out_size, void* d_ws, size_t ws_size,
                              hipStream_t stream)
{
  const float* x     = (const float*)d_in[0];
  const float* Wq    = (const float*)d_in[1];
  const float* bq    = (const float*)d_in[2];
  const float* Wk    = (const float*)d_in[3];
  const float* bk    = (const float*)d_in[4];
  const float* Wv    = (const float*)d_in[5];
  const float* bv    = (const float*)d_in[6];
  const float* W6    = (const float*)d_in[7];
  const float* b6    = (const float*)d_in[8];
  const float* gamma = (const float*)d_in[9];
  float* out = (float*)d_out;

  const size_t fixed = (size_t)N * DQ * 2 * 2        // qT,kT
                     + (size_t)CIN * N * 2            // vG
                     + (size_t)N * 4                  // e_buf
                     + 256;                           // sumExp (+pad)
  int nsl = 7;
  size_t need = fixed + (size_t)nsl * NT * 256 * 64 * 2 + (size_t)nsl * N * 4;
  if (ws_size < need) nsl = 4;
  const int totIters = N / 32;                        // 288
  const int base = totIters / nsl;
  const int rem  = totIters % nsl;

  char* ws = (char*)d_ws;
  const size_t OFF_QT = 0;
  const size_t OFF_KT = OFF_QT + (size_t)N * DQ * 2;
  const size_t OFF_V  = OFF_KT + (size_t)N * DQ * 2;
  const size_t OFF_OP = OFF_V  + (size_t)CIN * N * 2;
  const size_t OFF_LP = OFF_OP + (size_t)nsl * NT * 256 * 64 * 2;
  const size_t OFF_EB = OFF_LP + (size_t)nsl * N * 4;
  const size_t OFF_SE = OFF_EB + (size_t)N * 4;

  ushort_t* qT     = (ushort_t*)(ws + OFF_QT);
  ushort_t* kT     = (ushort_t*)(ws + OFF_KT);
  ushort_t* vG     = (ushort_t*)(ws + OFF_V);
  ushort_t* Opart  = (ushort_t*)(ws + OFF_OP);
  float*    lpart  = (float*)(ws + OFF_LP);
  float*    e_buf  = (float*)(ws + OFF_EB);
  float*    sumExp = (float*)(ws + OFF_SE);

  qkv_mfma<<<dim3(NT, 5), 256, 0, stream>>>(x, Wq, bq, Wk, bk, Wv, bv, qT, kT, vG, sumExp);
  attn_kernel<<<dim3(NT2, nsl), 512, 0, stream>>>(qT, kT, vG, Opart, lpart, base, rem);
  if (nsl == 7) cco_kernel<7><<<NT, 1024, 0, stream>>>(Opart, lpart, e_buf, sumExp);
  else          cco_kernel<4><<<NT, 1024, 0, stream>>>(Opart, lpart, e_buf, sumExp);
  final_mfma<<<dim3(NT, 4), 256, 0, stream>>>(x, W6, b6, gamma, e_buf, sumExp, out);
}